// Round 1
// baseline (22779.726 us; speedup 1.0000x reference)
//
#include <hip/hip_runtime.h>
#include <math.h>

#define TT   4096
#define HH   1500
#define NB   125     // blocks; each owns 12 hidden units
#define UPB  12      // units per block
#define NT   512     // threads per block (8 waves)

#define ALD(p)   __hip_atomic_load((p), __ATOMIC_RELAXED, __HIP_MEMORY_SCOPE_AGENT)
#define AST(p,v) __hip_atomic_store((p), (v), __ATOMIC_RELAXED, __HIP_MEMORY_SCOPE_AGENT)

__device__ __forceinline__ float fast_sigmoid(float z) {
  return 1.0f / (1.0f + __expf(-z));
}
__device__ __forceinline__ float fast_tanh(float z) {
  float az = fabsf(z);
  float e  = __expf(-2.0f * az);
  float r  = (1.0f - e) / (1.0f + e);
  return copysignf(r, z);
}

// Persistent kernel: W_hh lives in VGPRs (144 regs/lane), h(t) is exchanged
// via 64B "pub lines" (12 floats + step flag) in device memory with
// agent-scope write-through atomics. One LLC round trip per timestep.
__global__ __launch_bounds__(NT, 2) void lstm_fused(
    const float* __restrict__ x,    // (4096, 20)
    const float* __restrict__ Wih,  // (6000, 20)
    const float* __restrict__ Whh,  // (6000, 1500)
    const float* __restrict__ bih,  // (6000,)
    const float* __restrict__ bhh,  // (6000,)
    const float* __restrict__ W1,   // (1875, 1500)
    const float* __restrict__ b1,   // (1875,)
    const float* __restrict__ W2,   // (20, 1875)
    const float* __restrict__ b2,   // (20,)
    float* __restrict__ out,        // (20,)
    float* __restrict__ ws)
{
  const int tid = threadIdx.x;
  const int bid = blockIdx.x;
  const int wv  = tid >> 6;   // wave 0..7
  const int ln  = tid & 63;   // lane 0..63

  float* pub    = ws;               // [2][NB][16] floats: 12 h + flag(int) @12
  float* hidpub = ws + 2 * NB * 16; // [NB][16] floats: 15 hid + flag(int) @15

  __shared__ __align__(16) float lds_h[1536];   // h(t), zero-padded to 1536
  __shared__ __align__(16) float lds_x[20];     // x[t]
  __shared__ float lds_xp[48];                  // x-projection, 4 gates x 12 units
  __shared__ float lds_gsum[8][6];              // per-wave row sums
  __shared__ float lds_hid[15];
  __shared__ __align__(16) float lds_hd[1875];  // block 0 only

  if (tid >= 1500 - 36 + 0 && false) {}         // (no-op; keep structure simple)
  if (tid < 36) lds_h[1500 + tid] = 0.0f;       // zero pad tail once

  // ---- persistent W_hh slice in registers: 6 rows x 24 strided k per lane ----
  // wave wv handles gate (wv>>1), units [ (wv&1)*6, (wv&1)*6+6 ) of this block.
  const int gate = wv >> 1;
  const int uoff = (wv & 1) * 6;
  float w[6][24];
  #pragma unroll
  for (int r = 0; r < 6; ++r) {
    const int row = gate * HH + bid * UPB + uoff + r;
    const float* src = Whh + row * HH;
    #pragma unroll
    for (int m = 0; m < 24; ++m) {
      const int k = ln + 64 * m;                // strided: bank-conflict-free LDS reads
      w[r][m] = (k < HH) ? src[k] : 0.0f;
    }
  }

  // ---- x-projection duty: lanes 0..47 of wave 0, one (gate,unit) row each ----
  int rowx = 0; float biasx = 0.0f;
  const float4* wih4 = nullptr;
  if (tid < 48) {
    const int gx = tid / 12, dx = tid % 12;
    rowx  = gx * HH + bid * UPB + dx;
    biasx = bih[rowx] + bhh[rowx];
    wih4  = (const float4*)(Wih + rowx * 20);
  }

  float c = 0.0f;  // cell state, lanes 0..11 of wave 0 (unit = tid)

  // ---- init publish: h(0) = 0, flag = 0 ----
  if (tid < UPB) AST(pub + (0 * NB + bid) * 16 + tid, 0.0f);
  if (tid == 0)
    __hip_atomic_store((int*)(pub + (0 * NB + bid) * 16 + 12), 0,
                       __ATOMIC_RELEASE, __HIP_MEMORY_SCOPE_AGENT);

  for (int t = 0; t < TT; ++t) {
    const int s = t & 1;

    // issue W_ih row loads early (L2-hot; overlap with the poll round trip)
    float4 wr0, wr1, wr2, wr3, wr4;
    if (tid < 48) { wr0 = wih4[0]; wr1 = wih4[1]; wr2 = wih4[2]; wr3 = wih4[3]; wr4 = wih4[4]; }
    // stage x[t]
    if (wv == 7 && ln < 20) lds_x[ln] = x[20 * t + ln];

    // ---- poll + distribute h(t): lane j pulls 64B line of block j ----
    if (tid < NB) {
      float* line = pub + (s * NB + tid) * 16;
      while (__hip_atomic_load((int*)(line + 12), __ATOMIC_RELAXED,
                               __HIP_MEMORY_SCOPE_AGENT) != t) { }
      __builtin_amdgcn_fence(__ATOMIC_ACQUIRE, "workgroup");
      __asm__ __volatile__("" ::: "memory");
      float hv[12];
      #pragma unroll
      for (int i = 0; i < 12; ++i) hv[i] = ALD(line + i);
      float* dst = lds_h + tid * 12;   // 48B-aligned -> float4 stores OK
      *(float4*)(dst)     = make_float4(hv[0], hv[1], hv[2],  hv[3]);
      *(float4*)(dst + 4) = make_float4(hv[4], hv[5], hv[6],  hv[7]);
      *(float4*)(dst + 8) = make_float4(hv[8], hv[9], hv[10], hv[11]);
    }
    __syncthreads();   // (A) h(t) + x[t] staged

    // ---- x projection for this block's 48 gate rows ----
    if (tid < 48) {
      const float4* x4 = (const float4*)lds_x;
      const float4 xv0 = x4[0], xv1 = x4[1], xv2 = x4[2], xv3 = x4[3], xv4 = x4[4];
      float sx = biasx;
      sx += wr0.x*xv0.x + wr0.y*xv0.y + wr0.z*xv0.z + wr0.w*xv0.w;
      sx += wr1.x*xv1.x + wr1.y*xv1.y + wr1.z*xv1.z + wr1.w*xv1.w;
      sx += wr2.x*xv2.x + wr2.y*xv2.y + wr2.z*xv2.z + wr2.w*xv2.w;
      sx += wr3.x*xv3.x + wr3.y*xv3.y + wr3.z*xv3.z + wr3.w*xv3.w;
      sx += wr4.x*xv4.x + wr4.y*xv4.y + wr4.z*xv4.z + wr4.w*xv4.w;
      lds_xp[tid] = sx;
    }

    // ---- recurrent matvec from registers ----
    float hreg[24];
    #pragma unroll
    for (int m = 0; m < 24; ++m) hreg[m] = lds_h[ln + 64 * m];  // 2-way = free
    float acc[6];
    #pragma unroll
    for (int r = 0; r < 6; ++r) acc[r] = 0.0f;
    #pragma unroll
    for (int m = 0; m < 24; ++m) {
      #pragma unroll
      for (int r = 0; r < 6; ++r) acc[r] = fmaf(w[r][m], hreg[m], acc[r]);
    }
    #pragma unroll
    for (int r = 0; r < 6; ++r) {
      float v = acc[r];
      #pragma unroll
      for (int off = 32; off > 0; off >>= 1) v += __shfl_xor(v, off, 64);
      if (ln == 0) lds_gsum[wv][r] = v;
    }
    __syncthreads();   // (B) gate sums + xp ready

    // ---- gate nonlinearity + state update + publish (units = lanes 0..11) ----
    if (tid < UPB) {
      const int hh = tid / 6, jj = tid % 6;
      const float zi = lds_gsum[0 + hh][jj] + lds_xp[tid];
      const float zf = lds_gsum[2 + hh][jj] + lds_xp[12 + tid];
      const float zg = lds_gsum[4 + hh][jj] + lds_xp[24 + tid];
      const float zo = lds_gsum[6 + hh][jj] + lds_xp[36 + tid];
      const float ig = fast_sigmoid(zi);
      const float fg = fast_sigmoid(zf);
      const float og = fast_sigmoid(zo);
      const float gg = fast_tanh(zg);
      c = fg * c + ig * gg;
      const float hn = og * fast_tanh(c);
      AST(pub + ((s ^ 1) * NB + bid) * 16 + tid, hn);
    }
    if (tid == 0)
      __hip_atomic_store((int*)(pub + ((s ^ 1) * NB + bid) * 16 + 12), t + 1,
                         __ATOMIC_RELEASE, __HIP_MEMORY_SCOPE_AGENT);
  }

  // ---- fetch h(T) (slot 0, flag TT) ----
  if (tid < NB) {
    float* line = pub + (0 * NB + tid) * 16;
    while (__hip_atomic_load((int*)(line + 12), __ATOMIC_RELAXED,
                             __HIP_MEMORY_SCOPE_AGENT) != TT) { }
    __builtin_amdgcn_fence(__ATOMIC_ACQUIRE, "workgroup");
    __asm__ __volatile__("" ::: "memory");
    float hv[12];
    #pragma unroll
    for (int i = 0; i < 12; ++i) hv[i] = ALD(line + i);
    float* dst = lds_h + tid * 12;
    *(float4*)(dst)     = make_float4(hv[0], hv[1], hv[2],  hv[3]);
    *(float4*)(dst + 4) = make_float4(hv[4], hv[5], hv[6],  hv[7]);
    *(float4*)(dst + 8) = make_float4(hv[8], hv[9], hv[10], hv[11]);
  }
  __syncthreads();

  // ---- MLP layer 1: this block computes hid rows [bid*15, bid*15+15) ----
  for (int m = wv; m < 15; m += 8) {
    const int r = bid * 15 + m;
    const float4* wrow = (const float4*)(W1 + r * HH);  // 6000B rows: 16B aligned
    float ss = 0.0f;
    for (int k4 = ln; k4 < 375; k4 += 64) {
      const float4 a  = wrow[k4];
      const float4 hv = *(const float4*)(lds_h + 4 * k4);
      ss += a.x*hv.x + a.y*hv.y + a.z*hv.z + a.w*hv.w;
    }
    #pragma unroll
    for (int off = 32; off > 0; off >>= 1) ss += __shfl_xor(ss, off, 64);
    if (ln == 0) lds_hid[m] = ss + b1[r];
  }
  __syncthreads();
  if (tid < 15) AST(hidpub + bid * 16 + tid, lds_hid[tid]);
  if (tid == 0)
    __hip_atomic_store((int*)(hidpub + bid * 16 + 15), TT + 1,
                       __ATOMIC_RELEASE, __HIP_MEMORY_SCOPE_AGENT);
  if (bid != 0) return;

  // ---- block 0: gather hid, MLP layer 2, write out ----
  if (tid < NB) {
    float* line = hidpub + tid * 16;
    while (__hip_atomic_load((int*)(line + 15), __ATOMIC_RELAXED,
                             __HIP_MEMORY_SCOPE_AGENT) != TT + 1) { }
    __builtin_amdgcn_fence(__ATOMIC_ACQUIRE, "workgroup");
    __asm__ __volatile__("" ::: "memory");
    #pragma unroll
    for (int i = 0; i < 15; ++i) lds_hd[tid * 15 + i] = ALD(line + i);
  }
  __syncthreads();

  for (int r = wv; r < 20; r += 8) {
    float ss = 0.0f;
    for (int k = ln; k < 1875; k += 64) ss += W2[r * 1875 + k] * lds_hd[k];
    #pragma unroll
    for (int off = 32; off > 0; off >>= 1) ss += __shfl_xor(ss, off, 64);
    if (ln == 0) out[r] = ss + b2[r];
  }
}

extern "C" void kernel_launch(void* const* d_in, const int* in_sizes, int n_in,
                              void* d_out, int out_size, void* d_ws, size_t ws_size,
                              hipStream_t stream) {
  const float* x   = (const float*)d_in[0];
  const float* Wih = (const float*)d_in[1];
  const float* Whh = (const float*)d_in[2];
  const float* bih = (const float*)d_in[3];
  const float* bhh = (const float*)d_in[4];
  const float* W1  = (const float*)d_in[5];
  const float* b1  = (const float*)d_in[6];
  const float* W2  = (const float*)d_in[7];
  const float* b2  = (const float*)d_in[8];
  float* out = (float*)d_out;
  float* ws  = (float*)d_ws;   // uses 24,000 B: pub[2][125][16] + hidpub[125][16]

  // 125 blocks x 512 threads, >=1 block/CU resident (125 < 256 CUs) -> the
  // hand-rolled flag exchange cannot deadlock.
  hipLaunchKernelGGL(lstm_fused, dim3(NB), dim3(NT), 0, stream,
                     x, Wih, Whh, bih, bhh, W1, b1, W2, b2, out, ws);
}

// Round 2
// 17581.886 us; speedup vs baseline: 1.2956x; 1.2956x over previous
//
#include <hip/hip_runtime.h>
#include <math.h>

#define TT 4096
#define HH 1500
#define NB 250     // blocks; each owns 6 hidden units
#define NT 256     // 4 waves

typedef unsigned long long u64;

#define ALD8(p)   __hip_atomic_load((p), __ATOMIC_RELAXED, __HIP_MEMORY_SCOPE_AGENT)
#define ALD4(p)   __hip_atomic_load((p), __ATOMIC_RELAXED, __HIP_MEMORY_SCOPE_AGENT)
#define AST4(p,v) __hip_atomic_store((p), (v), __ATOMIC_RELAXED, __HIP_MEMORY_SCOPE_AGENT)

__device__ __forceinline__ float fast_sigmoid(float z) {
  return 1.0f / (1.0f + __expf(-z));
}
__device__ __forceinline__ float fast_tanh(float z) {
  float az = fabsf(z);
  float e  = __expf(-2.0f * az);
  float r  = (1.0f - e) / (1.0f + e);
  return copysignf(r, z);
}

// Persistent kernel. W_hh slice lives in VGPRs (36 float4 = 144 regs/lane,
// cap 512 via launch_bounds(256,1) so the allocator has 2x headroom — R1's
// spill was caused by the 256-reg cap). h(t) exchange: each published fp32
// carries a 4-bit step tag in its low mantissa bits, so one 24B atomic read
// of a block's line gives data+validity in a single LLC round trip.
__global__ __launch_bounds__(NT, 1) void lstm_fused(
    const float* __restrict__ x,    // (4096, 20)
    const float* __restrict__ Wih,  // (6000, 20)
    const float* __restrict__ Whh,  // (6000, 1500)
    const float* __restrict__ bih,  // (6000,)
    const float* __restrict__ bhh,  // (6000,)
    const float* __restrict__ W1,   // (1875, 1500)
    const float* __restrict__ b1,   // (1875,)
    const float* __restrict__ W2,   // (20, 1875)
    const float* __restrict__ b2,   // (20,)
    float* __restrict__ out,        // (20,)
    unsigned* __restrict__ ws)
{
  const int tid = threadIdx.x;
  const int bid = blockIdx.x;
  const int wv  = tid >> 6;   // wave 0..3  (= gate index i,f,g,o)
  const int ln  = tid & 63;

  unsigned* pub  = ws;          // [2][NB][8] dwords: 6 tagged h + pad (32B lines)
  unsigned* hidp = ws + 4096;   // [1875] tagged hid values

  __shared__ __align__(16) float lds_h[1536];   // h(t), zero-padded
  __shared__ __align__(16) float lds_x[20];
  __shared__ float lds_xp[24];                  // x-proj: [gate][unit]
  __shared__ float lds_gs[4][6];                // recurrent sums: [gate][unit]
  __shared__ __align__(16) float lds_hd[1875];  // block 0 only

  if (tid < 36) lds_h[1500 + tid] = 0.0f;       // zero pad once

  // ---- resident W_hh slice: wave wv = gate wv, units 0..5 of this block ----
  float4 w[6][6];
  {
    const float4* wh4 = (const float4*)Whh;     // rows are 375 float4 each
    #pragma unroll
    for (int u = 0; u < 6; ++u) {
      const float4* src = wh4 + (size_t)(wv * HH + bid * 6 + u) * 375;
      #pragma unroll
      for (int m = 0; m < 6; ++m) {
        const int idx = ln + 64 * m;
        w[u][m] = (idx < 375) ? src[idx] : make_float4(0.f, 0.f, 0.f, 0.f);
      }
    }
  }

  // ---- x-projection rows: lanes 0..5 of wave wv -> row (gate wv, unit ln) ----
  float4 wx0, wx1, wx2, wx3, wx4;
  float bias = 0.f;
  if (ln < 6) {
    const int row = wv * HH + bid * 6 + ln;
    const float4* s = (const float4*)(Wih + row * 20);
    wx0 = s[0]; wx1 = s[1]; wx2 = s[2]; wx3 = s[3]; wx4 = s[4];
    bias = bih[row] + bhh[row];
  }

  float c = 0.f;  // cell state (threads 0..5, unit = tid)

  // init publish: h(0)=0 with tag 1 (tag(h(k)) = (k+1)&15)
  if (tid < 6) AST4(pub + (0 * NB + bid) * 8 + tid, 1u);

  float xreg = 0.f;
  if (wv == 3 && ln < 20) xreg = x[ln];   // prefetch x[0]

  for (int t = 0; t < TT; ++t) {
    const int s = t & 1;
    const unsigned tag = (unsigned)((t + 1) & 15);

    if (wv == 3 && ln < 20) {
      lds_x[ln] = xreg;                       // stage x[t] (already in reg)
      if (t + 1 < TT) xreg = x[20 * (t + 1) + ln];  // prefetch x[t+1]
    }

    // ---- poll + gather h(t): lane j pulls block j's 24B tagged line ----
    if (tid < NB) {
      const u64* line = (const u64*)(pub + (s * NB + tid) * 8);
      u64 p0, p1, p2;
      for (;;) {
        p0 = ALD8(line + 0); p1 = ALD8(line + 1); p2 = ALD8(line + 2);
        unsigned m = (((unsigned)p0) & 15u) ^ tag;
        m |= (((unsigned)(p0 >> 32)) & 15u) ^ tag;
        m |= (((unsigned)p1) & 15u) ^ tag;
        m |= (((unsigned)(p1 >> 32)) & 15u) ^ tag;
        m |= (((unsigned)p2) & 15u) ^ tag;
        m |= (((unsigned)(p2 >> 32)) & 15u) ^ tag;
        if (!m) break;
        __builtin_amdgcn_s_sleep(1);
      }
      float2* dst = (float2*)(lds_h + tid * 6);
      dst[0] = make_float2(__uint_as_float((unsigned)p0), __uint_as_float((unsigned)(p0 >> 32)));
      dst[1] = make_float2(__uint_as_float((unsigned)p1), __uint_as_float((unsigned)(p1 >> 32)));
      dst[2] = make_float2(__uint_as_float((unsigned)p2), __uint_as_float((unsigned)(p2 >> 32)));
    }
    __syncthreads();   // (A) h(t) + x[t] staged

    // ---- x projection (lanes 0..5 of each wave) ----
    if (ln < 6) {
      const float4* x4 = (const float4*)lds_x;
      const float4 a = x4[0], b4 = x4[1], c4 = x4[2], d4 = x4[3], e4 = x4[4];
      float sx = bias;
      sx += wx0.x*a.x  + wx0.y*a.y  + wx0.z*a.z  + wx0.w*a.w;
      sx += wx1.x*b4.x + wx1.y*b4.y + wx1.z*b4.z + wx1.w*b4.w;
      sx += wx2.x*c4.x + wx2.y*c4.y + wx2.z*c4.z + wx2.w*c4.w;
      sx += wx3.x*d4.x + wx3.y*d4.y + wx3.z*d4.z + wx3.w*d4.w;
      sx += wx4.x*e4.x + wx4.y*e4.y + wx4.z*e4.z + wx4.w*e4.w;
      lds_xp[wv * 6 + ln] = sx;
    }

    // ---- recurrent matvec from registers ----
    float4 hr[6];
    {
      const float4* h4 = (const float4*)lds_h;
      #pragma unroll
      for (int m = 0; m < 6; ++m) hr[m] = h4[ln + 64 * m];  // conflict-free b128
    }
    float acc[6];
    #pragma unroll
    for (int u = 0; u < 6; ++u) {
      float sum = 0.f;
      #pragma unroll
      for (int m = 0; m < 6; ++m) {
        sum = fmaf(w[u][m].x, hr[m].x, sum);
        sum = fmaf(w[u][m].y, hr[m].y, sum);
        sum = fmaf(w[u][m].z, hr[m].z, sum);
        sum = fmaf(w[u][m].w, hr[m].w, sum);
      }
      acc[u] = sum;
    }
    #pragma unroll
    for (int u = 0; u < 6; ++u) {
      float v = acc[u];
      #pragma unroll
      for (int off = 32; off > 0; off >>= 1) v += __shfl_xor(v, off, 64);
      if (ln == 0) lds_gs[wv][u] = v;
    }
    __syncthreads();   // (B) sums + xp ready

    // ---- gates + state update + tagged publish (threads 0..5) ----
    if (tid < 6) {
      const int u = tid;
      const float zi = lds_gs[0][u] + lds_xp[u];
      const float zf = lds_gs[1][u] + lds_xp[6 + u];
      const float zg = lds_gs[2][u] + lds_xp[12 + u];
      const float zo = lds_gs[3][u] + lds_xp[18 + u];
      const float ig = fast_sigmoid(zi);
      const float fg = fast_sigmoid(zf);
      const float gg = fast_tanh(zg);
      const float og = fast_sigmoid(zo);
      c = fg * c + ig * gg;
      const float hn = og * fast_tanh(c);
      const unsigned bits = (__float_as_uint(hn) & ~15u) | (unsigned)((t + 2) & 15);
      AST4(pub + (((t + 1) & 1) * NB + bid) * 8 + u, bits);
    }
  }

  // ---- gather h(TT): slot 0, tag (TT+1)&15 = 1 ----
  {
    const unsigned tagf = (unsigned)((TT + 1) & 15);
    if (tid < NB) {
      const u64* line = (const u64*)(pub + (0 * NB + tid) * 8);
      u64 p0, p1, p2;
      for (;;) {
        p0 = ALD8(line + 0); p1 = ALD8(line + 1); p2 = ALD8(line + 2);
        unsigned m = (((unsigned)p0) & 15u) ^ tagf;
        m |= (((unsigned)(p0 >> 32)) & 15u) ^ tagf;
        m |= (((unsigned)p1) & 15u) ^ tagf;
        m |= (((unsigned)(p1 >> 32)) & 15u) ^ tagf;
        m |= (((unsigned)p2) & 15u) ^ tagf;
        m |= (((unsigned)(p2 >> 32)) & 15u) ^ tagf;
        if (!m) break;
        __builtin_amdgcn_s_sleep(1);
      }
      float2* dst = (float2*)(lds_h + tid * 6);
      dst[0] = make_float2(__uint_as_float((unsigned)p0), __uint_as_float((unsigned)(p0 >> 32)));
      dst[1] = make_float2(__uint_as_float((unsigned)p1), __uint_as_float((unsigned)(p1 >> 32)));
      dst[2] = make_float2(__uint_as_float((unsigned)p2), __uint_as_float((unsigned)(p2 >> 32)));
    }
  }
  __syncthreads();

  // ---- MLP layer 1: block computes rows r = bid + 250*i ----
  {
    const float4* h4 = (const float4*)lds_h;
    for (int i = wv; i < 8; i += 4) {
      const int r = bid + 250 * i;
      if (r < 1875) {
        const float4* wrow = (const float4*)(W1 + (size_t)r * HH);
        float ss = 0.f;
        #pragma unroll
        for (int m = 0; m < 6; ++m) {
          const int idx = ln + 64 * m;
          if (idx < 375) {
            const float4 a = wrow[idx], hv = h4[idx];
            ss += a.x*hv.x + a.y*hv.y + a.z*hv.z + a.w*hv.w;
          }
        }
        #pragma unroll
        for (int off = 32; off > 0; off >>= 1) ss += __shfl_xor(ss, off, 64);
        if (ln == 0) {
          const float v = ss + b1[r];
          AST4(hidp + r, (__float_as_uint(v) & ~15u) | 5u);  // tag 5 (!= poison 10)
        }
      }
    }
  }
  if (bid != 0) return;

  // ---- block 0: gather hid, MLP layer 2, write out ----
  for (int j = tid; j < 1875; j += NT) {
    unsigned bts;
    for (;;) {
      bts = ALD4(hidp + j);
      if ((bts & 15u) == 5u) break;
      __builtin_amdgcn_s_sleep(1);
    }
    lds_hd[j] = __uint_as_float(bts);
  }
  __syncthreads();

  for (int r = wv; r < 20; r += 4) {
    float ss = 0.f;
    for (int k = ln; k < 1875; k += 64)
      ss = fmaf(W2[(size_t)r * 1875 + k], lds_hd[k], ss);
    #pragma unroll
    for (int off = 32; off > 0; off >>= 1) ss += __shfl_xor(ss, off, 64);
    if (ln == 0) out[r] = ss + b2[r];
  }
}

extern "C" void kernel_launch(void* const* d_in, const int* in_sizes, int n_in,
                              void* d_out, int out_size, void* d_ws, size_t ws_size,
                              hipStream_t stream) {
  const float* x   = (const float*)d_in[0];
  const float* Wih = (const float*)d_in[1];
  const float* Whh = (const float*)d_in[2];
  const float* bih = (const float*)d_in[3];
  const float* bhh = (const float*)d_in[4];
  const float* W1  = (const float*)d_in[5];
  const float* b1  = (const float*)d_in[6];
  const float* W2  = (const float*)d_in[7];
  const float* b2  = (const float*)d_in[8];
  float* out   = (float*)d_out;
  unsigned* ws = (unsigned*)d_ws;   // uses ~24 KB

  // 250 blocks x 256 threads: capacity >= 2 blocks/CU even at ~230 VGPR,
  // so all blocks are co-resident -> the tagged-line exchange cannot deadlock.
  hipLaunchKernelGGL(lstm_fused, dim3(NB), dim3(NT), 0, stream,
                     x, Wih, Whh, bih, bhh, W1, b1, W2, b2, out, ws);
}

// Round 3
// 17249.631 us; speedup vs baseline: 1.3206x; 1.0193x over previous
//
#include <hip/hip_runtime.h>
#include <math.h>

#define TT 4096
#define HH 1500
#define NB 250     // blocks; each owns 6 hidden units
#define NT 256     // 4 waves

typedef unsigned long long u64;

#define ALD8(p)   __hip_atomic_load((p), __ATOMIC_RELAXED, __HIP_MEMORY_SCOPE_AGENT)
#define ALD4(p)   __hip_atomic_load((p), __ATOMIC_RELAXED, __HIP_MEMORY_SCOPE_AGENT)
#define AST4(p,v) __hip_atomic_store((p), (v), __ATOMIC_RELAXED, __HIP_MEMORY_SCOPE_AGENT)

__device__ __forceinline__ float fast_sigmoid(float z) {
  return 1.0f / (1.0f + __expf(-z));
}
__device__ __forceinline__ float fast_tanh(float z) {
  float az = fabsf(z);
  float e  = __expf(-2.0f * az);
  float r  = (1.0f - e) / (1.0f + e);
  return copysignf(r, z);
}

// Persistent kernel. W_hh slice pinned in VGPRs: R2 showed the RA
// *rematerializes* read-only loads instead of keeping them live (VGPR=108,
// 147 GB LLC re-read, 8.4 TB/s = LLC ceiling). The empty asm volatile makes
// each weight the result of an opaque op -> not remat-able -> 144 VGPRs of
// weights stay resident (budget 512 at 1 wave/EU). h(t) exchange: each
// published fp32 carries a 4-bit step tag in its low mantissa bits -> one
// 24B atomic read gives data+validity in a single LLC round trip.
__global__ __launch_bounds__(NT, 1) void lstm_fused(
    const float* __restrict__ x,    // (4096, 20)
    const float* __restrict__ Wih,  // (6000, 20)
    const float* __restrict__ Whh,  // (6000, 1500)
    const float* __restrict__ bih,  // (6000,)
    const float* __restrict__ bhh,  // (6000,)
    const float* __restrict__ W1,   // (1875, 1500)
    const float* __restrict__ b1,   // (1875,)
    const float* __restrict__ W2,   // (20, 1875)
    const float* __restrict__ b2,   // (20,)
    float* __restrict__ out,        // (20,)
    unsigned* __restrict__ ws)
{
  const int tid = threadIdx.x;
  const int bid = blockIdx.x;
  const int wv  = tid >> 6;   // wave 0..3  (= gate index i,f,g,o)
  const int ln  = tid & 63;

  unsigned* pub  = ws;          // [2][NB][8] dwords: 6 tagged h + pad (32B lines)
  unsigned* hidp = ws + 4096;   // [1875] tagged hid values

  __shared__ __align__(16) float lds_h[1536];   // h(t), zero-padded
  __shared__ __align__(16) float lds_x[20];
  __shared__ float lds_xp[24];                  // x-proj: [gate][unit]
  __shared__ float lds_gs[4][6];                // recurrent sums: [gate][unit]
  __shared__ __align__(16) float lds_hd[1875];  // block 0 only

  if (tid < 36) lds_h[1500 + tid] = 0.0f;       // zero pad once

  // ---- resident W_hh slice: wave wv = gate wv, units 0..5 of this block ----
  // scalar layout w[u][4*m+c] = W_hh[gate wv, unit u][4*(ln+64m)+c]
  float w[6][24];
  {
    const float4* wh4 = (const float4*)Whh;     // rows are 375 float4 each
    #pragma unroll
    for (int u = 0; u < 6; ++u) {
      const float4* src = wh4 + (size_t)(wv * HH + bid * 6 + u) * 375;
      #pragma unroll
      for (int m = 0; m < 6; ++m) {
        const int idx = ln + 64 * m;
        const float4 v = (idx < 375) ? src[idx] : make_float4(0.f, 0.f, 0.f, 0.f);
        w[u][4*m+0] = v.x; w[u][4*m+1] = v.y; w[u][4*m+2] = v.z; w[u][4*m+3] = v.w;
      }
    }
  }
  // Pin: opaque op kills rematerialization; values must stay in VGPRs.
  #pragma unroll
  for (int u = 0; u < 6; ++u) {
    #pragma unroll
    for (int i = 0; i < 24; ++i) {
      asm volatile("" : "+v"(w[u][i]));
    }
  }

  // ---- x-projection rows: lanes 0..5 of wave wv -> row (gate wv, unit ln) ----
  float4 wx0, wx1, wx2, wx3, wx4;
  float bias = 0.f;
  if (ln < 6) {
    const int row = wv * HH + bid * 6 + ln;
    const float4* s = (const float4*)(Wih + row * 20);
    wx0 = s[0]; wx1 = s[1]; wx2 = s[2]; wx3 = s[3]; wx4 = s[4];
    bias = bih[row] + bhh[row];
  }

  float c = 0.f;  // cell state (threads 0..5, unit = tid)

  // init publish: h(0)=0 with tag 1 (tag(h(k)) = (k+1)&15)
  if (tid < 6) AST4(pub + (0 * NB + bid) * 8 + tid, 1u);

  float xreg = 0.f;
  if (wv == 3 && ln < 20) xreg = x[ln];   // prefetch x[0]

  for (int t = 0; t < TT; ++t) {
    const int s = t & 1;
    const unsigned tag = (unsigned)((t + 1) & 15);

    if (wv == 3 && ln < 20) {
      lds_x[ln] = xreg;                       // stage x[t] (already in reg)
      if (t + 1 < TT) xreg = x[20 * (t + 1) + ln];  // prefetch x[t+1]
    }

    // ---- poll + gather h(t): lane j pulls block j's 24B tagged line ----
    if (tid < NB) {
      const u64* line = (const u64*)(pub + (s * NB + tid) * 8);
      u64 p0, p1, p2;
      for (;;) {
        p0 = ALD8(line + 0); p1 = ALD8(line + 1); p2 = ALD8(line + 2);
        unsigned m = (((unsigned)p0) & 15u) ^ tag;
        m |= (((unsigned)(p0 >> 32)) & 15u) ^ tag;
        m |= (((unsigned)p1) & 15u) ^ tag;
        m |= (((unsigned)(p1 >> 32)) & 15u) ^ tag;
        m |= (((unsigned)p2) & 15u) ^ tag;
        m |= (((unsigned)(p2 >> 32)) & 15u) ^ tag;
        if (!m) break;
        __builtin_amdgcn_s_sleep(1);
      }
      float2* dst = (float2*)(lds_h + tid * 6);
      dst[0] = make_float2(__uint_as_float((unsigned)p0), __uint_as_float((unsigned)(p0 >> 32)));
      dst[1] = make_float2(__uint_as_float((unsigned)p1), __uint_as_float((unsigned)(p1 >> 32)));
      dst[2] = make_float2(__uint_as_float((unsigned)p2), __uint_as_float((unsigned)(p2 >> 32)));
    }
    __syncthreads();   // (A) h(t) + x[t] staged

    // ---- x projection (lanes 0..5 of each wave) ----
    if (ln < 6) {
      const float4* x4 = (const float4*)lds_x;
      const float4 a = x4[0], b4 = x4[1], c4 = x4[2], d4 = x4[3], e4 = x4[4];
      float sx = bias;
      sx += wx0.x*a.x  + wx0.y*a.y  + wx0.z*a.z  + wx0.w*a.w;
      sx += wx1.x*b4.x + wx1.y*b4.y + wx1.z*b4.z + wx1.w*b4.w;
      sx += wx2.x*c4.x + wx2.y*c4.y + wx2.z*c4.z + wx2.w*c4.w;
      sx += wx3.x*d4.x + wx3.y*d4.y + wx3.z*d4.z + wx3.w*d4.w;
      sx += wx4.x*e4.x + wx4.y*e4.y + wx4.z*e4.z + wx4.w*e4.w;
      lds_xp[wv * 6 + ln] = sx;
    }

    // ---- recurrent matvec from registers ----
    float4 hr[6];
    {
      const float4* h4 = (const float4*)lds_h;
      #pragma unroll
      for (int m = 0; m < 6; ++m) hr[m] = h4[ln + 64 * m];  // conflict-free b128
    }
    float acc[6];
    #pragma unroll
    for (int u = 0; u < 6; ++u) {
      float sum = 0.f;
      #pragma unroll
      for (int m = 0; m < 6; ++m) {
        sum = fmaf(w[u][4*m+0], hr[m].x, sum);
        sum = fmaf(w[u][4*m+1], hr[m].y, sum);
        sum = fmaf(w[u][4*m+2], hr[m].z, sum);
        sum = fmaf(w[u][4*m+3], hr[m].w, sum);
      }
      acc[u] = sum;
    }
    #pragma unroll
    for (int u = 0; u < 6; ++u) {
      float v = acc[u];
      #pragma unroll
      for (int off = 32; off > 0; off >>= 1) v += __shfl_xor(v, off, 64);
      if (ln == 0) lds_gs[wv][u] = v;
    }
    __syncthreads();   // (B) sums + xp ready

    // ---- gates + state update + tagged publish (threads 0..5) ----
    if (tid < 6) {
      const int u = tid;
      const float zi = lds_gs[0][u] + lds_xp[u];
      const float zf = lds_gs[1][u] + lds_xp[6 + u];
      const float zg = lds_gs[2][u] + lds_xp[12 + u];
      const float zo = lds_gs[3][u] + lds_xp[18 + u];
      const float ig = fast_sigmoid(zi);
      const float fg = fast_sigmoid(zf);
      const float gg = fast_tanh(zg);
      const float og = fast_sigmoid(zo);
      c = fg * c + ig * gg;
      const float hn = og * fast_tanh(c);
      const unsigned bits = (__float_as_uint(hn) & ~15u) | (unsigned)((t + 2) & 15);
      AST4(pub + (((t + 1) & 1) * NB + bid) * 8 + u, bits);
    }
  }

  // ---- gather h(TT): slot 0, tag (TT+1)&15 = 1 ----
  {
    const unsigned tagf = (unsigned)((TT + 1) & 15);
    if (tid < NB) {
      const u64* line = (const u64*)(pub + (0 * NB + tid) * 8);
      u64 p0, p1, p2;
      for (;;) {
        p0 = ALD8(line + 0); p1 = ALD8(line + 1); p2 = ALD8(line + 2);
        unsigned m = (((unsigned)p0) & 15u) ^ tagf;
        m |= (((unsigned)(p0 >> 32)) & 15u) ^ tagf;
        m |= (((unsigned)p1) & 15u) ^ tagf;
        m |= (((unsigned)(p1 >> 32)) & 15u) ^ tagf;
        m |= (((unsigned)p2) & 15u) ^ tagf;
        m |= (((unsigned)(p2 >> 32)) & 15u) ^ tagf;
        if (!m) break;
        __builtin_amdgcn_s_sleep(1);
      }
      float2* dst = (float2*)(lds_h + tid * 6);
      dst[0] = make_float2(__uint_as_float((unsigned)p0), __uint_as_float((unsigned)(p0 >> 32)));
      dst[1] = make_float2(__uint_as_float((unsigned)p1), __uint_as_float((unsigned)(p1 >> 32)));
      dst[2] = make_float2(__uint_as_float((unsigned)p2), __uint_as_float((unsigned)(p2 >> 32)));
    }
  }
  __syncthreads();

  // ---- MLP layer 1: block computes rows r = bid + 250*i ----
  {
    const float4* h4 = (const float4*)lds_h;
    for (int i = wv; i < 8; i += 4) {
      const int r = bid + 250 * i;
      if (r < 1875) {
        const float4* wrow = (const float4*)(W1 + (size_t)r * HH);
        float ss = 0.f;
        #pragma unroll
        for (int m = 0; m < 6; ++m) {
          const int idx = ln + 64 * m;
          if (idx < 375) {
            const float4 a = wrow[idx], hv = h4[idx];
            ss += a.x*hv.x + a.y*hv.y + a.z*hv.z + a.w*hv.w;
          }
        }
        #pragma unroll
        for (int off = 32; off > 0; off >>= 1) ss += __shfl_xor(ss, off, 64);
        if (ln == 0) {
          const float v = ss + b1[r];
          AST4(hidp + r, (__float_as_uint(v) & ~15u) | 5u);  // tag 5 (!= poison 10)
        }
      }
    }
  }
  if (bid != 0) return;

  // ---- block 0: gather hid, MLP layer 2, write out ----
  for (int j = tid; j < 1875; j += NT) {
    unsigned bts;
    for (;;) {
      bts = ALD4(hidp + j);
      if ((bts & 15u) == 5u) break;
      __builtin_amdgcn_s_sleep(1);
    }
    lds_hd[j] = __uint_as_float(bts);
  }
  __syncthreads();

  for (int r = wv; r < 20; r += 4) {
    float ss = 0.f;
    for (int k = ln; k < 1875; k += 64)
      ss = fmaf(W2[(size_t)r * 1875 + k], lds_hd[k], ss);
    #pragma unroll
    for (int off = 32; off > 0; off >>= 1) ss += __shfl_xor(ss, off, 64);
    if (ln == 0) out[r] = ss + b2[r];
  }
}

extern "C" void kernel_launch(void* const* d_in, const int* in_sizes, int n_in,
                              void* d_out, int out_size, void* d_ws, size_t ws_size,
                              hipStream_t stream) {
  const float* x   = (const float*)d_in[0];
  const float* Wih = (const float*)d_in[1];
  const float* Whh = (const float*)d_in[2];
  const float* bih = (const float*)d_in[3];
  const float* bhh = (const float*)d_in[4];
  const float* W1  = (const float*)d_in[5];
  const float* b1  = (const float*)d_in[6];
  const float* W2  = (const float*)d_in[7];
  const float* b2  = (const float*)d_in[8];
  float* out   = (float*)d_out;
  unsigned* ws = (unsigned*)d_ws;   // uses ~24 KB

  // 250 blocks x 256 threads: capacity >= 1 block/CU on 256 CUs,
  // so all blocks are co-resident -> the tagged-line exchange cannot deadlock.
  hipLaunchKernelGGL(lstm_fused, dim3(NB), dim3(NT), 0, stream,
                     x, Wih, Whh, bih, bhh, W1, b1, W2, b2, out, ws);
}